// Round 3
// baseline (585.014 us; speedup 1.0000x reference)
//
#include <hip/hip_runtime.h>
#include <hip/hip_cooperative_groups.h>
#include <math.h>

namespace cg = cooperative_groups;

#define EPSV 1e-5f

__device__ __forceinline__ float fast_rcp(float x) {
#if __has_builtin(__builtin_amdgcn_rcpf)
    return __builtin_amdgcn_rcpf(x);
#else
    return 1.0f / x;
#endif
}

__device__ __forceinline__ float sigmoidf_(float x) {
    return fast_rcp(1.0f + __expf(-x));
}

// Phase D (tiny) and phase E (19 KB) never live at the same time.
union SharedU {
    struct { float x2m[64]; float x11L[64]; float sL[32]; } d;
    struct {
        float swf[64 * 64];   // 16 KB  sigmoid(w-gate) for whole bg
        float shf[64 * 8];    //  2 KB  sigmoid(h-gate) for the 8-row band
        float eL[64];
        float gL[32], dL[32], aL[32], bL[32];
    } e;
};

// PHASE: -1 = fused cooperative (grid-stride, grid.sync between phases),
//        0..4 = discrete fallback kernels.
template<int PHASE>
__global__ __launch_bounds__(256, 2) void mega(
    const float* __restrict__ x,
    const float* __restrict__ W, const float* __restrict__ Wb,
    const float* __restrict__ gnw, const float* __restrict__ gnb,
    const float* __restrict__ gn1w, const float* __restrict__ gn1b,
    const float* __restrict__ cwt, const float* __restrict__ cbs,
    const float* __restrict__ swt, const float* __restrict__ sbs,
    float* __restrict__ out, float* __restrict__ ws)
{
    __shared__ SharedU sm;

    float* rowmean = ws;                    // [8192][64]
    float* colmean = rowmean + 524288;
    float* shg     = colmean + 524288;      // [8192][64] sigmoided gates
    float* swg     = shg + 524288;
    float* meanA   = swg + 524288;          // [8192]
    float* varA    = meanA + 8192;
    float* meanT   = varA + 8192;
    float* varT    = meanT + 8192;
    float* spat    = varT + 8192;           // [128][32]
    float* eArr    = spat + 4096;           // [128][64]
    float* gArr    = eArr + 8192;           // [128][32]
    float* dArr    = gArr + 4096;
    float* aArr    = dArr + 4096;
    float* bArr    = aArr + 4096;
    float* kArr    = bArr + 4096;           // [128]

    const int t = threadIdx.x;
    const int l = t & 63;
    const int wv = t >> 6;
    const int stride = gridDim.x;

    // ============ Phase A: per-plane row/col/plane stats (per-wave) ========
    if (PHASE < 0 || PHASE == 0) {
      for (int u = blockIdx.x; u < 2048; u += stride) {
        int plane = u * 4 + wv;
        const float4* p4 = (const float4*)(x + (size_t)plane * 4096);
        float c0 = 0.f, c1 = 0.f, c2 = 0.f, c3 = 0.f, s = 0.f, ss = 0.f;
#pragma unroll 4
        for (int k = 0; k < 16; ++k) {
            float4 v = p4[k * 64 + l];
            float rp = v.x + v.y + v.z + v.w;
            s += rp;
            ss += v.x * v.x + v.y * v.y + v.z * v.z + v.w * v.w;
            c0 += v.x; c1 += v.y; c2 += v.z; c3 += v.w;
#pragma unroll
            for (int m = 8; m >= 1; m >>= 1) rp += __shfl_xor(rp, m, 16);
            if ((l & 15) == 0)
                rowmean[(size_t)plane * 64 + k * 4 + (l >> 4)] = rp * (1.f / 64.f);
        }
#pragma unroll
        for (int m = 32; m >= 16; m >>= 1) {
            c0 += __shfl_xor(c0, m); c1 += __shfl_xor(c1, m);
            c2 += __shfl_xor(c2, m); c3 += __shfl_xor(c3, m);
        }
        if (l < 16) {
            float4 cm = { c0 * (1.f / 64.f), c1 * (1.f / 64.f),
                          c2 * (1.f / 64.f), c3 * (1.f / 64.f) };
            ((float4*)(colmean + (size_t)plane * 64))[l] = cm;
        }
#pragma unroll
        for (int m = 32; m >= 1; m >>= 1) { s += __shfl_xor(s, m); ss += __shfl_xor(ss, m); }
        if (l == 0) {
            float mn = s * (1.f / 4096.f);
            meanA[plane] = mn;
            varA[plane] = ss * (1.f / 4096.f) - mn * mn;
        }
      }
    }
    if constexpr (PHASE < 0) cg::this_grid().sync();

    // ============ Phase B: 64x64 conv1x1 + sigmoid =========================
    if (PHASE < 0 || PHASE == 1) {
      for (int u = blockIdx.x; u < 256; u += stride) {
        int bgc = u >> 1, rc = u & 1;
        const float* rm = (rc ? colmean : rowmean) + (size_t)bgc * 4096;
        float* outp = (rc ? swg : shg) + (size_t)bgc * 4096;
        float r[64];
#pragma unroll
        for (int i = 0; i < 64; ++i) r[i] = rm[i * 64 + l];
        for (int jj = 0; jj < 16; ++jj) {
            int c = wv * 16 + jj;
            float acc = Wb[c];
#pragma unroll
            for (int i = 0; i < 64; ++i) acc = fmaf(W[c * 64 + i], r[i], acc);
            outp[c * 64 + l] = sigmoidf_(acc);
        }
      }
    }
    if constexpr (PHASE < 0) cg::this_grid().sync();

    // ============ Phase C: stats of t = x*sh*sw; spatial channel means =====
    if (PHASE < 0 || PHASE == 2) {
      for (int u = blockIdx.x; u < 2048; u += stride) {
        int plane = u * 4 + wv;
        int cch = plane & 63, bgc = plane >> 6;
        const float4* p4 = (const float4*)(x + (size_t)plane * 4096);
        float4 sw4 = ((const float4*)(swg + (size_t)plane * 64))[l & 15];
        float a = 0.f, bb = 0.f;
        bool spatial = (cch >= 32);
        if (spatial) {
            int i = cch - 32;
            float mu = meanA[plane];
            float r2 = rsqrtf(varA[plane] + EPSV);
            a = swt[i] * gn1w[i] * r2;
            bb = swt[i] * (gn1b[i] - mu * r2 * gn1w[i]) + sbs[i];
        }
        float st = 0.f, sst = 0.f, ssp = 0.f;
#pragma unroll 4
        for (int k = 0; k < 16; ++k) {
            float4 v = p4[k * 64 + l];
            float sh = shg[(size_t)plane * 64 + k * 4 + (l >> 4)];
            float t0 = v.x * sh * sw4.x;
            float t1 = v.y * sh * sw4.y;
            float t2 = v.z * sh * sw4.z;
            float t3 = v.w * sh * sw4.w;
            st += t0 + t1 + t2 + t3;
            sst += t0 * t0 + t1 * t1 + t2 * t2 + t3 * t3;
            if (spatial) {
                ssp += v.x * sigmoidf_(fmaf(a, v.x, bb))
                     + v.y * sigmoidf_(fmaf(a, v.y, bb))
                     + v.z * sigmoidf_(fmaf(a, v.z, bb))
                     + v.w * sigmoidf_(fmaf(a, v.w, bb));
            }
        }
#pragma unroll
        for (int m = 32; m >= 1; m >>= 1) {
            st += __shfl_xor(st, m); sst += __shfl_xor(sst, m); ssp += __shfl_xor(ssp, m);
        }
        if (l == 0) {
            float mn = st * (1.f / 4096.f);
            meanT[plane] = mn;
            varT[plane] = sst * (1.f / 4096.f) - mn * mn;
            if (spatial) spat[bgc * 32 + (cch - 32)] = ssp * (1.f / 4096.f);
        }
      }
    }
    if constexpr (PHASE < 0) cg::this_grid().sync();

    // ============ Phase D: softmaxes + coefficient folding =================
    if (PHASE < 0 || PHASE == 3) {
      for (int u = blockIdx.x; u < 128; u += stride) {
        int bgc = u;
        if (t < 32) {
            size_t idx = (size_t)bgc * 64 + t;
            float xc = meanA[idx];
            float s = sigmoidf_(fmaf(cwt[t], xc, cbs[t]));
            sm.d.sL[t] = s;
            sm.d.x2m[2 * t] = s * xc;              // mean of x_channel[t]
            sm.d.x2m[2 * t + 1] = spat[bgc * 32 + t];
        }
        __syncthreads();
        if (t < 64) {
            int c = t;
            size_t idx = (size_t)bgc * 64 + c;
            float v1 = gnb[c];
            float mx = v1;
#pragma unroll
            for (int m = 32; m >= 1; m >>= 1) mx = fmaxf(mx, __shfl_xor(mx, m));
            float e1 = __expf(v1 - mx);
            float s1 = e1;
#pragma unroll
            for (int m = 32; m >= 1; m >>= 1) s1 += __shfl_xor(s1, m);
            sm.d.x11L[c] = e1 / s1;

            float v2 = sm.d.x2m[c];
            mx = v2;
#pragma unroll
            for (int m = 32; m >= 1; m >>= 1) mx = fmaxf(mx, __shfl_xor(mx, m));
            float e2 = __expf(v2 - mx);
            float s2 = e2;
#pragma unroll
            for (int m = 32; m >= 1; m >>= 1) s2 += __shfl_xor(s2, m);
            float x21 = e2 / s2;

            float mt = meanT[idx];
            float rt = rsqrtf(varT[idx] + EPSV);
            eArr[idx] = x21 * gnw[c] * rt;
            float kp = x21 * (gnb[c] - gnw[c] * rt * mt);
#pragma unroll
            for (int m = 32; m >= 1; m >>= 1) kp += __shfl_xor(kp, m);
            if (c == 0) kArr[bgc] = kp;
        }
        __syncthreads();
        if (t < 32) {
            gArr[bgc * 32 + t] = sm.d.x11L[2 * t] * sm.d.sL[t];
            dArr[bgc * 32 + t] = sm.d.x11L[2 * t + 1];
            size_t idx2 = (size_t)bgc * 64 + 32 + t;
            float mu = meanA[idx2];
            float r2 = rsqrtf(varA[idx2] + EPSV);
            aArr[bgc * 32 + t] = swt[t] * gn1w[t] * r2;
            bArr[bgc * 32 + t] = swt[t] * (gn1b[t] - mu * r2 * gn1w[t]) + sbs[t];
        }
        __syncthreads();
      }
    }
    if constexpr (PHASE < 0) cg::this_grid().sync();

    // ============ Phase E: weights + output (1024 units of 8 rows) =========
    if (PHASE < 0 || PHASE == 4) {
      for (int u = blockIdx.x; u < 1024; u += stride) {
        int bgc = u >> 3, band = u & 7;
        int h0 = band * 8;
        // stage w-gates for the whole bg (layout identical to swg flat)
#pragma unroll
        for (int j = 0; j < 4; ++j) {
            int f = t + 256 * j;   // float4 index 0..1023
            ((float4*)sm.e.swf)[f] = ((const float4*)swg)[(size_t)bgc * 1024 + f];
        }
        // stage h-gates for this 8-row band
#pragma unroll
        for (int j = 0; j < 2; ++j) {
            int idx = t + 256 * j;  // 0..511
            int c = idx >> 3, r = idx & 7;
            sm.e.shf[c * 8 + r] = shg[(size_t)bgc * 4096 + c * 64 + h0 + r];
        }
        if (t < 64)       sm.e.eL[t]       = eArr[(size_t)bgc * 64 + t];
        else if (t < 96)  sm.e.gL[t - 64]  = gArr[bgc * 32 + t - 64];
        else if (t < 128) sm.e.dL[t - 96]  = dArr[bgc * 32 + t - 96];
        else if (t < 160) sm.e.aL[t - 128] = aArr[bgc * 32 + t - 128];
        else if (t < 192) sm.e.bL[t - 160] = bArr[bgc * 32 + t - 160];
        float K = kArr[bgc];
        __syncthreads();

        int hl = t >> 5, w2 = t & 31;    // row in band, float2 column
        const float* xp = x + (size_t)bgc * 262144 + (size_t)(h0 + hl) * 64 + w2 * 2;
        float ax = K, ay = K;
#pragma unroll 8
        for (int c = 0; c < 32; ++c) {
            float2 v = *(const float2*)(xp + (size_t)c * 4096);
            float ce = sm.e.eL[c] * sm.e.shf[c * 8 + hl];
            float gc = sm.e.gL[c];
            ax = fmaf(fmaf(ce, sm.e.swf[c * 64 + 2 * w2], gc), v.x, ax);
            ay = fmaf(fmaf(ce, sm.e.swf[c * 64 + 2 * w2 + 1], gc), v.y, ay);
        }
#pragma unroll 8
        for (int i = 0; i < 32; ++i) {
            int c = 32 + i;
            float2 v = *(const float2*)(xp + (size_t)c * 4096);
            float ce = sm.e.eL[c] * sm.e.shf[c * 8 + hl];
            float ai = sm.e.aL[i], bi = sm.e.bL[i], di = sm.e.dL[i];
            ax = fmaf(ce * sm.e.swf[c * 64 + 2 * w2], v.x, ax);
            ax = fmaf(di * v.x, sigmoidf_(fmaf(ai, v.x, bi)), ax);
            ay = fmaf(ce * sm.e.swf[c * 64 + 2 * w2 + 1], v.y, ay);
            ay = fmaf(di * v.y, sigmoidf_(fmaf(ai, v.y, bi)), ay);
        }
        float sx = sigmoidf_(ax), sy = sigmoidf_(ay);
        float* op = out + (xp - x);
#pragma unroll 8
        for (int c = 0; c < 64; ++c) {
            float2 v = *(const float2*)(xp + (size_t)c * 4096);
            float2 o = { v.x * sx, v.y * sy };
            *(float2*)(op + (size_t)c * 4096) = o;
        }
        __syncthreads();
      }
    }
}

// ---------------------------------------------------------------------------
extern "C" void kernel_launch(void* const* d_in, const int* in_sizes, int n_in,
                              void* d_out, int out_size, void* d_ws, size_t ws_size,
                              hipStream_t stream) {
    (void)in_sizes; (void)n_in; (void)out_size; (void)ws_size;
    const float* x    = (const float*)d_in[0];
    const float* W    = (const float*)d_in[1];
    const float* Wb   = (const float*)d_in[2];
    const float* gnw  = (const float*)d_in[3];
    const float* gnb  = (const float*)d_in[4];
    const float* gn1w = (const float*)d_in[5];
    const float* gn1b = (const float*)d_in[6];
    const float* cwt  = (const float*)d_in[7];
    const float* cbs  = (const float*)d_in[8];
    const float* swt  = (const float*)d_in[9];
    const float* sbs  = (const float*)d_in[10];
    float* out = (float*)d_out;
    float* ws = (float*)d_ws;

    bool launched = false;
    int dev = 0;
    hipGetDevice(&dev);
    int coopAttr = 0, nCU = 0;
    hipDeviceGetAttribute(&coopAttr, hipDeviceAttributeCooperativeLaunch, dev);
    hipDeviceGetAttribute(&nCU, hipDeviceAttributeMultiprocessorCount, dev);
    auto kfn = mega<-1>;
    int maxb = 0;
    if (coopAttr && nCU > 0 &&
        hipOccupancyMaxActiveBlocksPerMultiprocessor(
            &maxb, reinterpret_cast<const void*>(kfn), 256, 0) == hipSuccess &&
        maxb > 0) {
        int nb = maxb * nCU;
        if (nb > 2048) nb = 2048;
        void* args[] = { (void*)&x, (void*)&W, (void*)&Wb, (void*)&gnw, (void*)&gnb,
                         (void*)&gn1w, (void*)&gn1b, (void*)&cwt, (void*)&cbs,
                         (void*)&swt, (void*)&sbs, (void*)&out, (void*)&ws };
        if (hipLaunchCooperativeKernel(reinterpret_cast<const void*>(kfn),
                                       dim3(nb), dim3(256), args, 0, stream)
            == hipSuccess)
            launched = true;
    }
    if (!launched) {
        mega<0><<<2048, 256, 0, stream>>>(x, W, Wb, gnw, gnb, gn1w, gn1b,
                                          cwt, cbs, swt, sbs, out, ws);
        mega<1><<<256, 256, 0, stream>>>(x, W, Wb, gnw, gnb, gn1w, gn1b,
                                         cwt, cbs, swt, sbs, out, ws);
        mega<2><<<2048, 256, 0, stream>>>(x, W, Wb, gnw, gnb, gn1w, gn1b,
                                          cwt, cbs, swt, sbs, out, ws);
        mega<3><<<128, 256, 0, stream>>>(x, W, Wb, gnw, gnb, gn1w, gn1b,
                                         cwt, cbs, swt, sbs, out, ws);
        mega<4><<<1024, 256, 0, stream>>>(x, W, Wb, gnw, gnb, gn1w, gn1b,
                                          cwt, cbs, swt, sbs, out, ws);
    }
}

// Round 6
// 340.762 us; speedup vs baseline: 1.7168x; 1.7168x over previous
//
#include <hip/hip_runtime.h>
#include <math.h>

#define EPSV 1e-5f

typedef float vfloat4 __attribute__((ext_vector_type(4)));

__device__ __forceinline__ float fast_rcp(float x) {
#if __has_builtin(__builtin_amdgcn_rcpf)
    return __builtin_amdgcn_rcpf(x);
#else
    return 1.0f / x;
#endif
}

__device__ __forceinline__ float sigmoidf_(float x) {
    return fast_rcp(1.0f + __expf(-x));
}

// ---------------------------------------------------------------------------
// K_A: per-plane row/col/plane stats. Wave-per-plane, no LDS, no barriers.
// grid = 2048 x 256 (4 waves = 4 planes per block).
// Lane l, float4 f = k*64+l : row = k*4 + (l>>4), cols 4*(l&15)..+3.
// ---------------------------------------------------------------------------
__global__ __launch_bounds__(256) void k_statsA(
    const float* __restrict__ x,
    float* __restrict__ rowmean,   // [8192][64]
    float* __restrict__ colmean,   // [8192][64]
    float* __restrict__ meanA,     // [8192]
    float* __restrict__ varA)      // [8192]
{
    const int t = threadIdx.x, l = t & 63, wv = t >> 6;
    const int plane = blockIdx.x * 4 + wv;
    const float4* p4 = (const float4*)(x + (size_t)plane * 4096);
    float c0 = 0.f, c1 = 0.f, c2 = 0.f, c3 = 0.f, s = 0.f, ss = 0.f;
#pragma unroll 8
    for (int k = 0; k < 16; ++k) {
        float4 v = p4[k * 64 + l];
        float rp = v.x + v.y + v.z + v.w;
        s += rp;
        ss += v.x * v.x + v.y * v.y + v.z * v.z + v.w * v.w;
        c0 += v.x; c1 += v.y; c2 += v.z; c3 += v.w;
#pragma unroll
        for (int m = 8; m >= 1; m >>= 1) rp += __shfl_xor(rp, m, 16);
        if ((l & 15) == 0)
            rowmean[(size_t)plane * 64 + k * 4 + (l >> 4)] = rp * (1.f / 64.f);
    }
#pragma unroll
    for (int m = 32; m >= 16; m >>= 1) {
        c0 += __shfl_xor(c0, m); c1 += __shfl_xor(c1, m);
        c2 += __shfl_xor(c2, m); c3 += __shfl_xor(c3, m);
    }
    if (l < 16) {
        float4 cm = { c0 * (1.f / 64.f), c1 * (1.f / 64.f),
                      c2 * (1.f / 64.f), c3 * (1.f / 64.f) };
        ((float4*)(colmean + (size_t)plane * 64))[l] = cm;
    }
#pragma unroll
    for (int m = 32; m >= 1; m >>= 1) { s += __shfl_xor(s, m); ss += __shfl_xor(ss, m); }
    if (l == 0) {
        float mn = s * (1.f / 4096.f);
        meanA[plane] = mn;
        varA[plane] = ss * (1.f / 4096.f) - mn * mn;
    }
}

// ---------------------------------------------------------------------------
// K_B: 64x64 conv1x1 over row/col means + sigmoid. grid = 256 x 256.
// ---------------------------------------------------------------------------
__global__ __launch_bounds__(256) void k_conv(
    const float* __restrict__ W, const float* __restrict__ Wb,
    const float* __restrict__ rowmean, const float* __restrict__ colmean,
    float* __restrict__ shg, float* __restrict__ swg)
{
    int blk = blockIdx.x;
    int bg = blk >> 1, rc = blk & 1;
    const float* rm = (rc ? colmean : rowmean) + (size_t)bg * 4096;
    float* outp = (rc ? swg : shg) + (size_t)bg * 4096;
    int t = threadIdx.x, lane = t & 63, wv = t >> 6;
    float r[64];
#pragma unroll
    for (int i = 0; i < 64; ++i) r[i] = rm[i * 64 + lane];
    for (int j = 0; j < 16; ++j) {
        int c = wv * 16 + j;
        float acc = Wb[c];
#pragma unroll
        for (int i = 0; i < 64; ++i)
            acc = fmaf(W[c * 64 + i], r[i], acc);
        outp[c * 64 + lane] = sigmoidf_(acc);
    }
}

// ---------------------------------------------------------------------------
// K_C: stats of t = x*sh*sw; spatial channel means. Wave-per-plane.
// grid = 2048 x 256.
// ---------------------------------------------------------------------------
__global__ __launch_bounds__(256) void k_statsC(
    const float* __restrict__ x,
    const float* __restrict__ shg, const float* __restrict__ swg,
    const float* __restrict__ meanA, const float* __restrict__ varA,
    const float* __restrict__ swt, const float* __restrict__ sbs,
    const float* __restrict__ gn1w, const float* __restrict__ gn1b,
    float* __restrict__ meanT, float* __restrict__ varT,
    float* __restrict__ spat)   // [128][32]
{
    const int t = threadIdx.x, l = t & 63, wv = t >> 6;
    const int plane = blockIdx.x * 4 + wv;
    const int cch = plane & 63, bgc = plane >> 6;
    const float4* p4 = (const float4*)(x + (size_t)plane * 4096);
    float4 sw4 = ((const float4*)(swg + (size_t)plane * 64))[l & 15];
    float a = 0.f, bb = 0.f;
    const bool spatial = (cch >= 32);
    if (spatial) {
        int i = cch - 32;
        float mu = meanA[plane];
        float r2 = rsqrtf(varA[plane] + EPSV);
        a = swt[i] * gn1w[i] * r2;
        bb = swt[i] * (gn1b[i] - mu * r2 * gn1w[i]) + sbs[i];
    }
    float st = 0.f, sst = 0.f, ssp = 0.f;
#pragma unroll 8
    for (int k = 0; k < 16; ++k) {
        float4 v = p4[k * 64 + l];
        float sh = shg[(size_t)plane * 64 + k * 4 + (l >> 4)];
        float t0 = v.x * sh * sw4.x;
        float t1 = v.y * sh * sw4.y;
        float t2 = v.z * sh * sw4.z;
        float t3 = v.w * sh * sw4.w;
        st += t0 + t1 + t2 + t3;
        sst += t0 * t0 + t1 * t1 + t2 * t2 + t3 * t3;
        if (spatial) {
            ssp += v.x * sigmoidf_(fmaf(a, v.x, bb))
                 + v.y * sigmoidf_(fmaf(a, v.y, bb))
                 + v.z * sigmoidf_(fmaf(a, v.z, bb))
                 + v.w * sigmoidf_(fmaf(a, v.w, bb));
        }
    }
#pragma unroll
    for (int m = 32; m >= 1; m >>= 1) {
        st += __shfl_xor(st, m); sst += __shfl_xor(sst, m); ssp += __shfl_xor(ssp, m);
    }
    if (l == 0) {
        float mn = st * (1.f / 4096.f);
        meanT[plane] = mn;
        varT[plane] = sst * (1.f / 4096.f) - mn * mn;
        if (spatial) spat[bgc * 32 + (cch - 32)] = ssp * (1.f / 4096.f);
    }
}

// ---------------------------------------------------------------------------
// K_D: softmaxes + coefficient folding. grid = 128 x 64.
// ---------------------------------------------------------------------------
__global__ __launch_bounds__(64) void k_coef(
    const float* __restrict__ meanA, const float* __restrict__ varA,
    const float* __restrict__ meanT, const float* __restrict__ varT,
    const float* __restrict__ spat,
    const float* __restrict__ gnw, const float* __restrict__ gnb,
    const float* __restrict__ gn1w, const float* __restrict__ gn1b,
    const float* __restrict__ cwt, const float* __restrict__ cbs,
    const float* __restrict__ swt, const float* __restrict__ sbs,
    float* __restrict__ eArr, float* __restrict__ gArr,
    float* __restrict__ dArr, float* __restrict__ aArr,
    float* __restrict__ bArr, float* __restrict__ kArr)
{
    int bg = blockIdx.x;
    int c = threadIdx.x;                 // 0..63, one wave
    size_t idx = (size_t)bg * 64 + c;
    __shared__ float x2m[64], x11L[64], sL[32];
    if (c < 32) {
        float xc = meanA[idx];
        float s = sigmoidf_(fmaf(cwt[c], xc, cbs[c]));
        sL[c] = s;
        x2m[2 * c] = s * xc;             // mean of x_channel[c]
        x2m[2 * c + 1] = spat[bg * 32 + c];
    }
    __syncthreads();
    float v1 = gnb[c];
    float mx = v1;
#pragma unroll
    for (int m = 32; m >= 1; m >>= 1) mx = fmaxf(mx, __shfl_xor(mx, m));
    float e1 = __expf(v1 - mx);
    float s1 = e1;
#pragma unroll
    for (int m = 32; m >= 1; m >>= 1) s1 += __shfl_xor(s1, m);
    float x11 = e1 / s1;
    x11L[c] = x11;
    float v2 = x2m[c];
    mx = v2;
#pragma unroll
    for (int m = 32; m >= 1; m >>= 1) mx = fmaxf(mx, __shfl_xor(mx, m));
    float e2 = __expf(v2 - mx);
    float s2 = e2;
#pragma unroll
    for (int m = 32; m >= 1; m >>= 1) s2 += __shfl_xor(s2, m);
    float x21 = e2 / s2;

    float mt = meanT[idx];
    float rt = rsqrtf(varT[idx] + EPSV);
    eArr[idx] = x21 * gnw[c] * rt;
    float kp = x21 * (gnb[c] - gnw[c] * rt * mt);
#pragma unroll
    for (int m = 32; m >= 1; m >>= 1) kp += __shfl_xor(kp, m);
    if (c == 0) kArr[bg] = kp;
    __syncthreads();
    if (c < 32) {
        gArr[bg * 32 + c] = x11L[2 * c] * sL[c];
        dArr[bg * 32 + c] = x11L[2 * c + 1];
        size_t idx2 = (size_t)bg * 64 + 32 + c;
        float mu = meanA[idx2];
        float r2 = rsqrtf(varA[idx2] + EPSV);
        aArr[bg * 32 + c] = swt[c] * gn1w[c] * r2;
        bArr[bg * 32 + c] = swt[c] * (gn1b[c] - mu * r2 * gn1w[c]) + sbs[c];
    }
}

// ---------------------------------------------------------------------------
// K_E: weights + output. grid = 512 (bg*4 + quarter) x 256.
// Thread owns one float4 (4 px): hl = t>>4 (16 rows), w4 = t&15.
// Two passes over x (both L3-warm); nontemporal store for out.
// ---------------------------------------------------------------------------
__global__ __launch_bounds__(256) void k_final(
    const float* __restrict__ x,
    const float* __restrict__ shg, const float* __restrict__ swg,
    const float* __restrict__ eArr, const float* __restrict__ gArr,
    const float* __restrict__ dArr, const float* __restrict__ aArr,
    const float* __restrict__ bArr, const float* __restrict__ kArr,
    float* __restrict__ outp)
{
    const int blk = blockIdx.x;
    const int bg = blk >> 2, tile = blk & 3;
    const int h0 = tile << 4;
    const int t = threadIdx.x;
    __shared__ float swf[64 * 64];   // 16 KB  w-gates, whole bg
    __shared__ float shf[64 * 16];   //  4 KB  h-gates for the 16-row band
    __shared__ float eL[64], gL[32], dL[32], aL[32], bL[32];
#pragma unroll
    for (int j = 0; j < 4; ++j) {
        int f = t + 256 * j;         // float4 idx 0..1023
        ((float4*)swf)[f] = ((const float4*)swg)[(size_t)bg * 1024 + f];
    }
#pragma unroll
    for (int j = 0; j < 4; ++j) {
        int idx = t + 256 * j;       // 0..1023
        int c = idx >> 4, r = idx & 15;
        shf[idx] = shg[(size_t)bg * 4096 + c * 64 + h0 + r];
    }
    if (t < 64)       eL[t]       = eArr[(size_t)bg * 64 + t];
    else if (t < 96)  gL[t - 64]  = gArr[bg * 32 + t - 64];
    else if (t < 128) dL[t - 96]  = dArr[bg * 32 + t - 96];
    else if (t < 160) aL[t - 128] = aArr[bg * 32 + t - 128];
    else if (t < 192) bL[t - 160] = bArr[bg * 32 + t - 160];
    const float K = kArr[bg];
    __syncthreads();

    const int hl = t >> 4, w4 = t & 15;
    const float* xp = x + (size_t)bg * 262144 + (size_t)(h0 + hl) * 64 + w4 * 4;
    float ax = K, ay = K, az = K, aw = K;
#pragma unroll 8
    for (int c = 0; c < 32; ++c) {
        float4 v = *(const float4*)(xp + (size_t)c * 4096);
        float ce = eL[c] * shf[c * 16 + hl];
        float gc = gL[c];
        const float* swc = &swf[c * 64 + w4 * 4];
        ax = fmaf(fmaf(ce, swc[0], gc), v.x, ax);
        ay = fmaf(fmaf(ce, swc[1], gc), v.y, ay);
        az = fmaf(fmaf(ce, swc[2], gc), v.z, az);
        aw = fmaf(fmaf(ce, swc[3], gc), v.w, aw);
    }
#pragma unroll 8
    for (int i = 0; i < 32; ++i) {
        int c = 32 + i;
        float4 v = *(const float4*)(xp + (size_t)c * 4096);
        float ce = eL[c] * shf[c * 16 + hl];
        float ai = aL[i], bi = bL[i], di = dL[i];
        const float* swc = &swf[c * 64 + w4 * 4];
        ax = fmaf(ce * swc[0], v.x, ax); ax = fmaf(di * v.x, sigmoidf_(fmaf(ai, v.x, bi)), ax);
        ay = fmaf(ce * swc[1], v.y, ay); ay = fmaf(di * v.y, sigmoidf_(fmaf(ai, v.y, bi)), ay);
        az = fmaf(ce * swc[2], v.z, az); az = fmaf(di * v.z, sigmoidf_(fmaf(ai, v.z, bi)), az);
        aw = fmaf(ce * swc[3], v.w, aw); aw = fmaf(di * v.w, sigmoidf_(fmaf(ai, v.w, bi)), aw);
    }
    const float sx = sigmoidf_(ax), sy = sigmoidf_(ay),
                sz = sigmoidf_(az), sw_ = sigmoidf_(aw);
    float* op = outp + (xp - x);
#pragma unroll 8
    for (int c = 0; c < 64; ++c) {
        float4 v = *(const float4*)(xp + (size_t)c * 4096);
        vfloat4 o = { v.x * sx, v.y * sy, v.z * sz, v.w * sw_ };
        __builtin_nontemporal_store(o, (vfloat4*)(op + (size_t)c * 4096));
    }
}

// ---------------------------------------------------------------------------
extern "C" void kernel_launch(void* const* d_in, const int* in_sizes, int n_in,
                              void* d_out, int out_size, void* d_ws, size_t ws_size,
                              hipStream_t stream) {
    (void)in_sizes; (void)n_in; (void)out_size; (void)ws_size;
    const float* x    = (const float*)d_in[0];
    const float* W    = (const float*)d_in[1];
    const float* Wb   = (const float*)d_in[2];
    const float* gnw  = (const float*)d_in[3];
    const float* gnb  = (const float*)d_in[4];
    const float* gn1w = (const float*)d_in[5];
    const float* gn1b = (const float*)d_in[6];
    const float* cwt  = (const float*)d_in[7];
    const float* cbs  = (const float*)d_in[8];
    const float* swt  = (const float*)d_in[9];
    const float* sbs  = (const float*)d_in[10];
    float* out = (float*)d_out;
    float* ws = (float*)d_ws;

    float* rowmean = ws;                    // [8192][64]
    float* colmean = rowmean + 524288;
    float* shg     = colmean + 524288;      // sigmoided gates
    float* swg     = shg + 524288;
    float* meanA   = swg + 524288;
    float* varA    = meanA + 8192;
    float* meanT   = varA + 8192;
    float* varT    = meanT + 8192;
    float* spat    = varT + 8192;
    float* eArr    = spat + 4096;
    float* gArr    = eArr + 8192;
    float* dArr    = gArr + 4096;
    float* aArr    = dArr + 4096;
    float* bArr    = aArr + 4096;
    float* kArr    = bArr + 4096;

    k_statsA<<<2048, 256, 0, stream>>>(x, rowmean, colmean, meanA, varA);
    k_conv<<<256, 256, 0, stream>>>(W, Wb, rowmean, colmean, shg, swg);
    k_statsC<<<2048, 256, 0, stream>>>(x, shg, swg, meanA, varA, swt, sbs, gn1w, gn1b,
                                       meanT, varT, spat);
    k_coef<<<128, 64, 0, stream>>>(meanA, varA, meanT, varT, spat, gnw, gnb, gn1w, gn1b,
                                   cwt, cbs, swt, sbs, eArr, gArr, dArr, aArr, bArr, kArr);
    k_final<<<512, 256, 0, stream>>>(x, shg, swg, eArr, gArr, dArr, aArr, bArr, kArr, out);
}

// Round 7
// 321.352 us; speedup vs baseline: 1.8205x; 1.0604x over previous
//
#include <hip/hip_runtime.h>
#include <math.h>

#define EPSV 1e-5f

typedef float vfloat4 __attribute__((ext_vector_type(4)));

__device__ __forceinline__ float fast_rcp(float x) {
#if __has_builtin(__builtin_amdgcn_rcpf)
    return __builtin_amdgcn_rcpf(x);
#else
    return 1.0f / x;
#endif
}

__device__ __forceinline__ float sigmoidf_(float x) {
    return fast_rcp(1.0f + __expf(-x));
}

// ---------------------------------------------------------------------------
// K_A: per-plane row/col/plane stats. Wave-per-plane, no LDS, no barriers.
// grid = 2048 x 256 (4 waves = 4 planes per block).
// ---------------------------------------------------------------------------
__global__ __launch_bounds__(256) void k_statsA(
    const float* __restrict__ x,
    float* __restrict__ rowmean,   // [8192][64]
    float* __restrict__ colmean,   // [8192][64]
    float* __restrict__ meanA,     // [8192]
    float* __restrict__ varA)      // [8192]
{
    const int t = threadIdx.x, l = t & 63, wv = t >> 6;
    const int plane = blockIdx.x * 4 + wv;
    const float4* p4 = (const float4*)(x + (size_t)plane * 4096);
    float c0 = 0.f, c1 = 0.f, c2 = 0.f, c3 = 0.f, s = 0.f, ss = 0.f;
#pragma unroll 8
    for (int k = 0; k < 16; ++k) {
        float4 v = p4[k * 64 + l];
        float rp = v.x + v.y + v.z + v.w;
        s += rp;
        ss += v.x * v.x + v.y * v.y + v.z * v.z + v.w * v.w;
        c0 += v.x; c1 += v.y; c2 += v.z; c3 += v.w;
#pragma unroll
        for (int m = 8; m >= 1; m >>= 1) rp += __shfl_xor(rp, m, 16);
        if ((l & 15) == 0)
            rowmean[(size_t)plane * 64 + k * 4 + (l >> 4)] = rp * (1.f / 64.f);
    }
#pragma unroll
    for (int m = 32; m >= 16; m >>= 1) {
        c0 += __shfl_xor(c0, m); c1 += __shfl_xor(c1, m);
        c2 += __shfl_xor(c2, m); c3 += __shfl_xor(c3, m);
    }
    if (l < 16) {
        float4 cm = { c0 * (1.f / 64.f), c1 * (1.f / 64.f),
                      c2 * (1.f / 64.f), c3 * (1.f / 64.f) };
        ((float4*)(colmean + (size_t)plane * 64))[l] = cm;
    }
#pragma unroll
    for (int m = 32; m >= 1; m >>= 1) { s += __shfl_xor(s, m); ss += __shfl_xor(ss, m); }
    if (l == 0) {
        float mn = s * (1.f / 4096.f);
        meanA[plane] = mn;
        varA[plane] = ss * (1.f / 4096.f) - mn * mn;
    }
}

// ---------------------------------------------------------------------------
// K_B: 64x64 conv1x1 over row/col means + sigmoid. grid = 256 x 256.
// ---------------------------------------------------------------------------
__global__ __launch_bounds__(256) void k_conv(
    const float* __restrict__ W, const float* __restrict__ Wb,
    const float* __restrict__ rowmean, const float* __restrict__ colmean,
    float* __restrict__ shg, float* __restrict__ swg)
{
    int blk = blockIdx.x;
    int bg = blk >> 1, rc = blk & 1;
    const float* rm = (rc ? colmean : rowmean) + (size_t)bg * 4096;
    float* outp = (rc ? swg : shg) + (size_t)bg * 4096;
    int t = threadIdx.x, lane = t & 63, wv = t >> 6;
    float r[64];
#pragma unroll
    for (int i = 0; i < 64; ++i) r[i] = rm[i * 64 + lane];
    for (int j = 0; j < 16; ++j) {
        int c = wv * 16 + j;
        float acc = Wb[c];
#pragma unroll
        for (int i = 0; i < 64; ++i)
            acc = fmaf(W[c * 64 + i], r[i], acc);
        outp[c * 64 + lane] = sigmoidf_(acc);
    }
}

// ---------------------------------------------------------------------------
// K_C: stats of t = x*sh*sw; spatial channel means. Wave-per-plane.
// grid = 2048 x 256.
// ---------------------------------------------------------------------------
__global__ __launch_bounds__(256) void k_statsC(
    const float* __restrict__ x,
    const float* __restrict__ shg, const float* __restrict__ swg,
    const float* __restrict__ meanA, const float* __restrict__ varA,
    const float* __restrict__ swt, const float* __restrict__ sbs,
    const float* __restrict__ gn1w, const float* __restrict__ gn1b,
    float* __restrict__ meanT, float* __restrict__ varT,
    float* __restrict__ spat)   // [128][32]
{
    const int t = threadIdx.x, l = t & 63, wv = t >> 6;
    const int plane = blockIdx.x * 4 + wv;
    const int cch = plane & 63, bgc = plane >> 6;
    const float4* p4 = (const float4*)(x + (size_t)plane * 4096);
    float4 sw4 = ((const float4*)(swg + (size_t)plane * 64))[l & 15];
    float a = 0.f, bb = 0.f;
    const bool spatial = (cch >= 32);
    if (spatial) {
        int i = cch - 32;
        float mu = meanA[plane];
        float r2 = rsqrtf(varA[plane] + EPSV);
        a = swt[i] * gn1w[i] * r2;
        bb = swt[i] * (gn1b[i] - mu * r2 * gn1w[i]) + sbs[i];
    }
    float st = 0.f, sst = 0.f, ssp = 0.f;
#pragma unroll 8
    for (int k = 0; k < 16; ++k) {
        float4 v = p4[k * 64 + l];
        float sh = shg[(size_t)plane * 64 + k * 4 + (l >> 4)];
        float t0 = v.x * sh * sw4.x;
        float t1 = v.y * sh * sw4.y;
        float t2 = v.z * sh * sw4.z;
        float t3 = v.w * sh * sw4.w;
        st += t0 + t1 + t2 + t3;
        sst += t0 * t0 + t1 * t1 + t2 * t2 + t3 * t3;
        if (spatial) {
            ssp += v.x * sigmoidf_(fmaf(a, v.x, bb))
                 + v.y * sigmoidf_(fmaf(a, v.y, bb))
                 + v.z * sigmoidf_(fmaf(a, v.z, bb))
                 + v.w * sigmoidf_(fmaf(a, v.w, bb));
        }
    }
#pragma unroll
    for (int m = 32; m >= 1; m >>= 1) {
        st += __shfl_xor(st, m); sst += __shfl_xor(sst, m); ssp += __shfl_xor(ssp, m);
    }
    if (l == 0) {
        float mn = st * (1.f / 4096.f);
        meanT[plane] = mn;
        varT[plane] = sst * (1.f / 4096.f) - mn * mn;
        if (spatial) spat[bgc * 32 + (cch - 32)] = ssp * (1.f / 4096.f);
    }
}

// ---------------------------------------------------------------------------
// K_E2: fused coefficient-fold (wave 0) + weights + output; SINGLE x read.
// grid = 2048 (bg*16 + band of 4 rows) x 256.
// Thread: wave wv = ch-slice (16 ch), lane l = quad (row r = l>>4, qc = l&15).
// Each thread caches its 16 float4s of x, computes partial weight sum,
// LDS-reduce across 4 waves, sigmoid, rescale cached regs, store.
// ---------------------------------------------------------------------------
__global__ __launch_bounds__(256, 4) void k_final2(
    const float* __restrict__ x,
    const float* __restrict__ shg, const float* __restrict__ swg,
    const float* __restrict__ meanA, const float* __restrict__ varA,
    const float* __restrict__ meanT, const float* __restrict__ varT,
    const float* __restrict__ spat,
    const float* __restrict__ gnw, const float* __restrict__ gnb,
    const float* __restrict__ gn1w, const float* __restrict__ gn1b,
    const float* __restrict__ cwt, const float* __restrict__ cbs,
    const float* __restrict__ swt, const float* __restrict__ sbs,
    float* __restrict__ outp)
{
    const int blk = blockIdx.x;
    const int bg = blk >> 4, band = blk & 15;
    const int h0 = band << 2;                 // 4 rows per block
    const int t = threadIdx.x, l = t & 63, wv = t >> 6;

    __shared__ float swf[64 * 64];            // 16 KB  w-gates whole bg
    __shared__ float shf[64 * 4];             //  1 KB  h-gates [c*4 + r]
    __shared__ float eL[64], gL[32], dL[32], aL[32], bL[32];
    __shared__ float kS;
    __shared__ float4 red[4][64];             //  4 KB  partial sums
    __shared__ float4 sig4[64];               //  1 KB  sigmoid(weights)

    // ---- staging (all waves) ----
#pragma unroll
    for (int j = 0; j < 4; ++j) {
        int f = t + 256 * j;
        ((float4*)swf)[f] = ((const float4*)(swg + (size_t)bg * 4096))[f];
    }
    {
        int c = t >> 2, r = t & 3;
        shf[t] = shg[(size_t)bg * 4096 + c * 64 + h0 + r];
    }

    // ---- D-compute (wave 0 only; redundant per block, trivially cheap) ----
    if (wv == 0) {
        const int c = l;
        size_t idx = (size_t)bg * 64 + c;
        float Aj = 0.f, Bj = 0.f, scj = 0.f;
        if (c < 32) {
            float xc = meanA[idx];
            scj = sigmoidf_(fmaf(cwt[c], xc, cbs[c]));
            Aj = scj * xc;                     // mean of x_channel[c]
            Bj = spat[bg * 32 + c];            // mean of x_spatial[c]
        }
        float As = __shfl(Aj, c >> 1);
        float Bs = __shfl(Bj, c >> 1);
        float v2 = (c & 1) ? Bs : As;          // x2 channel mean
        // x11 = softmax(gn_b)
        float v1 = gnb[c];
        float mx = v1;
#pragma unroll
        for (int m = 32; m >= 1; m >>= 1) mx = fmaxf(mx, __shfl_xor(mx, m));
        float e1 = __expf(v1 - mx);
        float s1 = e1;
#pragma unroll
        for (int m = 32; m >= 1; m >>= 1) s1 += __shfl_xor(s1, m);
        float x11 = e1 / s1;
        // x21 = softmax(x2 channel means)
        mx = v2;
#pragma unroll
        for (int m = 32; m >= 1; m >>= 1) mx = fmaxf(mx, __shfl_xor(mx, m));
        float e2 = __expf(v2 - mx);
        float s2 = e2;
#pragma unroll
        for (int m = 32; m >= 1; m >>= 1) s2 += __shfl_xor(s2, m);
        float x21 = e2 / s2;

        float mT = meanT[idx];
        float rt = rsqrtf(varT[idx] + EPSV);
        float e_c = x21 * gnw[c] * rt;
        float kp = x21 * (gnb[c] - gnw[c] * rt * mT);
#pragma unroll
        for (int m = 32; m >= 1; m >>= 1) kp += __shfl_xor(kp, m);
        float x11e = __shfl(x11, (2 * c) & 63);
        float x11o = __shfl(x11, (2 * c + 1) & 63);
        eL[c] = e_c;
        if (c == 0) kS = kp;
        if (c < 32) {
            gL[c] = x11e * scj;
            dL[c] = x11o;
            size_t idx2 = (size_t)bg * 64 + 32 + c;
            float mu = meanA[idx2];
            float r2 = rsqrtf(varA[idx2] + EPSV);
            aL[c] = swt[c] * gn1w[c] * r2;
            bL[c] = swt[c] * (gn1b[c] - mu * r2 * gn1w[c]) + sbs[c];
        }
    }
    __syncthreads();

    // ---- main: cache x, partial weight sums ----
    const int r = l >> 4, qc = l & 15;
    const float* xp = x + (size_t)bg * 262144 + (size_t)(h0 + r) * 64 + qc * 4;
    const int c0 = wv * 16;
    float4 xc[16];
    float4 part = {0.f, 0.f, 0.f, 0.f};
    if (wv < 2) {
#pragma unroll
        for (int cc = 0; cc < 16; ++cc) {
            int c = c0 + cc;
            float4 v = *(const float4*)(xp + (size_t)c * 4096);
            xc[cc] = v;
            float ce = eL[c] * shf[c * 4 + r];
            float gc = gL[c];
            float4 s4 = *(const float4*)&swf[c * 64 + qc * 4];
            part.x = fmaf(fmaf(ce, s4.x, gc), v.x, part.x);
            part.y = fmaf(fmaf(ce, s4.y, gc), v.y, part.y);
            part.z = fmaf(fmaf(ce, s4.z, gc), v.z, part.z);
            part.w = fmaf(fmaf(ce, s4.w, gc), v.w, part.w);
        }
    } else {
#pragma unroll
        for (int cc = 0; cc < 16; ++cc) {
            int c = c0 + cc;
            int i = c - 32;
            float4 v = *(const float4*)(xp + (size_t)c * 4096);
            xc[cc] = v;
            float ce = eL[c] * shf[c * 4 + r];
            float ai = aL[i], bi = bL[i], di = dL[i];
            float4 s4 = *(const float4*)&swf[c * 64 + qc * 4];
            part.x = fmaf(ce * s4.x, v.x, part.x);
            part.x = fmaf(di * v.x, sigmoidf_(fmaf(ai, v.x, bi)), part.x);
            part.y = fmaf(ce * s4.y, v.y, part.y);
            part.y = fmaf(di * v.y, sigmoidf_(fmaf(ai, v.y, bi)), part.y);
            part.z = fmaf(ce * s4.z, v.z, part.z);
            part.z = fmaf(di * v.z, sigmoidf_(fmaf(ai, v.z, bi)), part.z);
            part.w = fmaf(ce * s4.w, v.w, part.w);
            part.w = fmaf(di * v.w, sigmoidf_(fmaf(ai, v.w, bi)), part.w);
        }
    }
    red[wv][l] = part;
    __syncthreads();
    if (wv == 0) {
        float4 p0 = red[0][l], p1 = red[1][l], p2 = red[2][l], p3 = red[3][l];
        float K = kS;
        float4 sgv;
        sgv.x = sigmoidf_(K + p0.x + p1.x + p2.x + p3.x);
        sgv.y = sigmoidf_(K + p0.y + p1.y + p2.y + p3.y);
        sgv.z = sigmoidf_(K + p0.z + p1.z + p2.z + p3.z);
        sgv.w = sigmoidf_(K + p0.w + p1.w + p2.w + p3.w);
        sig4[l] = sgv;
    }
    __syncthreads();
    const float4 sg = sig4[l];
    float* op = outp + (xp - x);
#pragma unroll
    for (int cc = 0; cc < 16; ++cc) {
        int c = c0 + cc;
        float4 v = xc[cc];
        vfloat4 o = { v.x * sg.x, v.y * sg.y, v.z * sg.z, v.w * sg.w };
        __builtin_nontemporal_store(o, (vfloat4*)(op + (size_t)c * 4096));
    }
}

// ---------------------------------------------------------------------------
extern "C" void kernel_launch(void* const* d_in, const int* in_sizes, int n_in,
                              void* d_out, int out_size, void* d_ws, size_t ws_size,
                              hipStream_t stream) {
    (void)in_sizes; (void)n_in; (void)out_size; (void)ws_size;
    const float* x    = (const float*)d_in[0];
    const float* W    = (const float*)d_in[1];
    const float* Wb   = (const float*)d_in[2];
    const float* gnw  = (const float*)d_in[3];
    const float* gnb  = (const float*)d_in[4];
    const float* gn1w = (const float*)d_in[5];
    const float* gn1b = (const float*)d_in[6];
    const float* cwt  = (const float*)d_in[7];
    const float* cbs  = (const float*)d_in[8];
    const float* swt  = (const float*)d_in[9];
    const float* sbs  = (const float*)d_in[10];
    float* out = (float*)d_out;
    float* ws = (float*)d_ws;

    float* rowmean = ws;                    // [8192][64]
    float* colmean = rowmean + 524288;
    float* shg     = colmean + 524288;      // sigmoided gates
    float* swg     = shg + 524288;
    float* meanA   = swg + 524288;
    float* varA    = meanA + 8192;
    float* meanT   = varA + 8192;
    float* varT    = meanT + 8192;
    float* spat    = varT + 8192;

    k_statsA<<<2048, 256, 0, stream>>>(x, rowmean, colmean, meanA, varA);
    k_conv<<<256, 256, 0, stream>>>(W, Wb, rowmean, colmean, shg, swg);
    k_statsC<<<2048, 256, 0, stream>>>(x, shg, swg, meanA, varA, swt, sbs, gn1w, gn1b,
                                       meanT, varT, spat);
    k_final2<<<2048, 256, 0, stream>>>(x, shg, swg, meanA, varA, meanT, varT, spat,
                                       gnw, gnb, gn1w, gn1b, cwt, cbs, swt, sbs, out);
}